// Round 15
// baseline (437.893 us; speedup 1.0000x reference)
//
#include <hip/hip_runtime.h>
#include <hip/hip_bf16.h>

// MockLlamaAttention R15: B=1, S=2048, HIDDEN=4096, H=32, HKV=8, D=128, G=4.
// Changes vs R13 (R14 fat-tile reverted): weight-convert kernels ELIMINATED.
// GEMMs read f32 weights directly: B reg-staged (4x coalesced f32x4/thread),
// converted in-register, ds_write_b64 into the same swizzled f16 LDS layout
// (write-side XOR = read-side XOR). A stays global_load_lds f16. LDS still
// 48KB -> 3 blocks/CU (R14 lost this). Counted-vmcnt ledger per wave (6
// VMEM/step): bar | vmcnt(2) | ds_write B(k+1) | issue B,A(k+2) | vmcnt(6) |
// lgkm(0) | bar | compute(k). Attention unchanged. Workspace: 75 MiB.

typedef _Float16 half4_t __attribute__((ext_vector_type(4)));
typedef _Float16 half8_t __attribute__((ext_vector_type(8)));
typedef float f32x4 __attribute__((ext_vector_type(4)));

#define S_LEN 2048
#define HID 4096
#define NH 32
#define NKV 8

__device__ __forceinline__ void gload_lds16(const void* g, void* l) {
  __builtin_amdgcn_global_load_lds((const __attribute__((address_space(1))) void*)g,
                                   (__attribute__((address_space(3))) void*)l, 16, 0, 0);
}

// ---------------- fp32 -> f16 convert (vectorized) ----------------
__global__ __launch_bounds__(256) void cvt_f32_f16(const float* __restrict__ src,
                                                   _Float16* __restrict__ dst, int n4) {
  int i = blockIdx.x * 256 + threadIdx.x;
  if (i >= n4) return;
  f32x4 v = *(const f32x4*)(src + (size_t)i * 4);
  half4_t h = {(_Float16)v[0], (_Float16)v[1], (_Float16)v[2], (_Float16)v[3]};
  *(half4_t*)(dst + (size_t)i * 4) = h;
}

// ---------------- RoPE cos/sin table: [2048][64] fp32 ----------------
__global__ __launch_bounds__(256) void rope_table_kernel(float* __restrict__ cost,
                                                         float* __restrict__ sint) {
  int i = blockIdx.x * 256 + threadIdx.x;
  int d = i & 63;
  int s = i >> 6;
  float inv = exp2f(-(float)d * (13.287712379549449f / 64.0f));
  float f = (float)s * inv;
  cost[i] = cosf(f);
  sint[i] = sinf(f);
}

// ---------------- RoPE apply for Q (in place, [S][NH*128]) ----------------
__global__ __launch_bounds__(256) void rope_apply_q(_Float16* __restrict__ X,
                                                    const float* __restrict__ cost,
                                                    const float* __restrict__ sint) {
  int idx = blockIdx.x * 256 + threadIdx.x;
  int g = idx & 15;
  int tmp = idx >> 4;
  int h = tmp % NH;
  int s = tmp / NH;
  int d0 = g * 4;
  size_t base = (size_t)s * HID + h * 128 + d0;
  half4_t x1 = *(half4_t*)(X + base);
  half4_t x2 = *(half4_t*)(X + base + 64);
  const float* cp = cost + s * 64 + d0;
  const float* sp = sint + s * 64 + d0;
  half4_t y1, y2;
#pragma unroll
  for (int j = 0; j < 4; ++j) {
    float c = cp[j], sn = sp[j];
    float a = (float)x1[j], b = (float)x2[j];
    y1[j] = (_Float16)(a * c - b * sn);
    y2[j] = (_Float16)(b * c + a * sn);
  }
  *(half4_t*)(X + base) = y1;
  *(half4_t*)(X + base + 64) = y2;
}

// ------- RoPE apply for K, in place on tiled K2 [NKV][S/16][d/8][16s][8d] ----
__global__ __launch_bounds__(256) void rope_k2_inplace(_Float16* __restrict__ K2,
                                                       const float* __restrict__ cost,
                                                       const float* __restrict__ sint) {
  int idx = blockIdx.x * 256 + threadIdx.x;  // S*NKV*16
  int g = idx & 15;
  int tmp = idx >> 4;
  int h = tmp % NKV;
  int s = tmp / NKV;
  int d0 = g * 4;
  size_t tb = (size_t)h * (S_LEN * 128) + (size_t)(s >> 4) * 2048 + (size_t)(s & 15) * 8;
  size_t a1 = tb + (size_t)(d0 >> 3) * 128 + (d0 & 7);
  size_t a2 = a1 + 1024;
  half4_t x1 = *(half4_t*)(K2 + a1);
  half4_t x2 = *(half4_t*)(K2 + a2);
  const float* cp = cost + s * 64 + d0;
  const float* sp = sint + s * 64 + d0;
  half4_t y1, y2;
#pragma unroll
  for (int j = 0; j < 4; ++j) {
    float c = cp[j], sn = sp[j];
    float a = (float)x1[j], b = (float)x2[j];
    y1[j] = (_Float16)(a * c - b * sn);
    y2[j] = (_Float16)(b * c + a * sn);
  }
  *(half4_t*)(K2 + a1) = y1;
  *(half4_t*)(K2 + a2) = y2;
}

// ======== GEMM: 128x128, BK=32, tri-buffer counted-vmcnt, f32 weights ========
// C = A[M,4096]f16 @ W[N,4096]f32^T. 4 waves, per-wave 64x64 (4x4 frags).
// A: global_load_lds (inverse-swizzled source). B: 4x f32x4 coalesced loads
// (8 lanes/row x 128B) -> cvt f16 -> ds_write_b64 at swizzled position.
// LDS 48KB: As/Bs[3][128*32] f16, T2 swizzle chunk^=(row>>1)&3.
// MODE 0 (QKV, 768 blocks): weight-once XCD decode; c<32 Q natural,
//   32..39 K2 scatter, 40..47 V2 scatter. MODE 1 (O-proj, 512): f32 C.
template <int MODE>
__global__ __launch_bounds__(256) void gemmD(const _Float16* __restrict__ A,
                                             const float* __restrict__ W0,
                                             const float* __restrict__ W1,
                                             const float* __restrict__ W2,
                                             void* __restrict__ out,
                                             _Float16* __restrict__ K2,
                                             _Float16* __restrict__ V2) {
  const int id = blockIdx.x;
  const int xcd = id & 7, slot = id >> 3;
  const int c = (MODE == 0) ? (xcd * 6 + (slot >> 4)) : (xcd * 4 + (slot >> 4));
  const int m0 = (slot & 15) * 128;
  const int col0 = c * 128;
  const float* Wsel;
  int colLoc;
  if (MODE == 0) {
    if (col0 < 4096)      { Wsel = W0; colLoc = col0; }
    else if (col0 < 5120) { Wsel = W1; colLoc = col0 - 4096; }
    else                  { Wsel = W2; colLoc = col0 - 5120; }
  } else {
    Wsel = W0; colLoc = col0;
  }
  __shared__ __align__(16) _Float16 As[3][128 * 32];
  __shared__ __align__(16) _Float16 Bs[3][128 * 32];
  const int t = threadIdx.x, w = t >> 6, l = t & 63, lr = l & 15, lg = l >> 4;
  const int wm = (w >> 1) * 64, wn = (w & 1) * 64;
  const int srow = l >> 2;
  const int scolS = (((l & 3) ^ ((l >> 3) & 3))) * 8;  // A-source swizzle (lane-const)
  const int rc = (lr >> 1) & 3;                        // read-side swizzle
  const _Float16* ap = A + (size_t)m0 * 4096 + scolS;
  const float* bw = Wsel + (size_t)colLoc * 4096;

  f32x4 acc[4][4] = {};
  f32x4 br[4];  // B staging regs (one tile: 4x f32x4/thread)

#define GLOADA(buf_, kb_)                                             \
  _Pragma("unroll") for (int it = 0; it < 2; ++it) {                  \
    const int ci = it * 4 + w;                                        \
    const int r = ci * 16 + srow;                                     \
    gload_lds16(ap + (size_t)r * 4096 + (kb_), &As[buf_][ci * 512]);  \
  }
#define LOADB(kb_)                                                    \
  _Pragma("unroll") for (int it = 0; it < 4; ++it) {                  \
    const int r = it * 32 + (t >> 3);                                 \
    br[it] = *(const f32x4*)(bw + (size_t)r * 4096 + (kb_) + (t & 7) * 4); \
  }
#define CVTW(buf_)                                                    \
  _Pragma("unroll") for (int it = 0; it < 4; ++it) {                  \
    const int r = it * 32 + (t >> 3);                                 \
    half4_t h;                                                        \
    _Pragma("unroll") for (int j = 0; j < 4; ++j) h[j] = (_Float16)br[it][j]; \
    const int fc = (t & 7) >> 1;                                      \
    *(half4_t*)&Bs[buf_][r * 32 + ((fc ^ ((r >> 1) & 3)) * 8) + (t & 1) * 4] = h; \
  }

  // prologue: tile0 (A->LDS, B->regs->LDS), tile1 (A->LDS, B->regs)
  LOADB(0)
  GLOADA(0, 0)
  asm volatile("s_waitcnt vmcnt(2)" ::: "memory");  // B-regs(0) landed
  __builtin_amdgcn_sched_barrier(0);
  CVTW(0)
  LOADB(32)
  GLOADA(1, 32)
  asm volatile("s_waitcnt lgkmcnt(0)" ::: "memory");  // publish B(0) write
  __builtin_amdgcn_sched_barrier(0);

  for (int k = 0; k < 128; ++k) {
    const int buf = k % 3;
    __builtin_amdgcn_s_barrier();
    asm volatile("s_waitcnt vmcnt(2)" ::: "memory");  // B-regs(k+1) landed
    __builtin_amdgcn_sched_barrier(0);
    if (k + 1 < 128) { CVTW((k + 1) % 3) }
    if (k + 2 < 128) {
      LOADB((k + 2) * 32)
      GLOADA((k + 2) % 3, (k + 2) * 32)
      asm volatile("s_waitcnt vmcnt(6)" ::: "memory");  // A(k+1) landed
    } else if (k == 127) {
      asm volatile("s_waitcnt vmcnt(0)" ::: "memory");  // tail drain
    }
    asm volatile("s_waitcnt lgkmcnt(0)" ::: "memory");  // publish B(k+1) write
    __builtin_amdgcn_sched_barrier(0);
    __builtin_amdgcn_s_barrier();
    half8_t af[4], bf[4];
#pragma unroll
    for (int mi = 0; mi < 4; ++mi)
      af[mi] = *(const half8_t*)&As[buf][(wm + mi * 16 + lr) * 32 + (lg ^ rc) * 8];
#pragma unroll
    for (int ni = 0; ni < 4; ++ni)
      bf[ni] = *(const half8_t*)&Bs[buf][(wn + ni * 16 + lr) * 32 + (lg ^ rc) * 8];
#pragma unroll
    for (int mi = 0; mi < 4; ++mi)
#pragma unroll
      for (int ni = 0; ni < 4; ++ni)
        acc[mi][ni] = __builtin_amdgcn_mfma_f32_16x16x32_f16(af[mi], bf[ni], acc[mi][ni], 0, 0, 0);
  }
#undef GLOADA
#undef LOADB
#undef CVTW

  // epilogue (R5-verified mappings)
#pragma unroll
  for (int mi = 0; mi < 4; ++mi) {
#pragma unroll
    for (int ni = 0; ni < 4; ++ni) {
      const int row = m0 + wm + mi * 16 + lg * 4;
      const int col = col0 + wn + ni * 16 + lr;
      if (MODE == 1) {
#pragma unroll
        for (int i = 0; i < 4; ++i)
          ((float*)out)[(size_t)(row + i) * 4096 + col] = acc[mi][ni][i];
      } else {
        if (col < 4096) {
#pragma unroll
          for (int i = 0; i < 4; ++i)
            ((_Float16*)out)[(size_t)(row + i) * 4096 + col] = (_Float16)acc[mi][ni][i];
        } else if (col < 5120) {  // K2 tiled [NKV][S/16][d/8][16s][8d]
          const int cl = col - 4096;
          const int h = cl >> 7, d = cl & 127;
          const size_t kk = (size_t)h * (S_LEN * 128) + (size_t)(row >> 4) * 2048 +
                            (size_t)(d >> 3) * 128 + (d & 7);
#pragma unroll
          for (int i = 0; i < 4; ++i)
            K2[kk + ((row + i) & 15) * 8] = (_Float16)acc[mi][ni][i];
        } else {  // V2 tiled [NKV][S/16][128d][16s]
          const int cl = col - 5120;
          half4_t o;
#pragma unroll
          for (int i = 0; i < 4; ++i) o[i] = (_Float16)acc[mi][ni][i];
          *(half4_t*)(V2 + (size_t)(cl >> 7) * (S_LEN * 128) + (size_t)(row >> 4) * 2048 +
                      (size_t)(cl & 127) * 16 + (row & 15)) = o;
        }
      }
    }
  }
}

// ---------------- Flash attention (split-KV, tiled K2/V2) — unchanged ---------
__global__ __launch_bounds__(256) void attn_kernel(const _Float16* __restrict__ Q,
                                                   const _Float16* __restrict__ K2,
                                                   const _Float16* __restrict__ V2,
                                                   _Float16* __restrict__ Op,
                                                   float* __restrict__ Md) {
  const int bid = blockIdx.x;
  const int hk = bid & 7;
  const int split = (bid >> 3) & 1;
  const int qt = 63 - (bid >> 4);
  const int w = threadIdx.x >> 6;
  const int h = hk * 4 + w;
  const int l = threadIdx.x & 63;
  const int lr = l & 15;
  const int lg = l >> 4;
  const float scale = 0.08838834764831845f;
  const float LOG2E = 1.4426950408889634f;
  const float NEG = -1.0e30f;

  const int half_steps = qt + 1;
  const int kt0 = split * half_steps;
  const int kt1 = kt0 + half_steps;

  int sq[2];
  half8_t qf[2][4];
#pragma unroll
  for (int qc = 0; qc < 2; ++qc) {
    sq[qc] = qt * 32 + qc * 16 + lr;
#pragma unroll
    for (int c = 0; c < 4; ++c)
      qf[qc][c] = *(const half8_t*)(Q + (size_t)sq[qc] * HID + h * 128 + c * 32 + lg * 8);
  }
  const _Float16* Kb = K2 + (size_t)hk * (S_LEN * 128);
  const _Float16* Vb = V2 + (size_t)hk * (S_LEN * 128);

  f32x4 acc[8][2] = {};
  float m[2] = {NEG, NEG};
  float den[2] = {0.f, 0.f};

  for (int kt = kt0; kt < kt1; ++kt) {
    half8_t kf[4];
#pragma unroll
    for (int c = 0; c < 4; ++c)
      kf[c] = *(const half8_t*)(Kb + (size_t)kt * 2048 + (c * 4 + lg) * 128 + lr * 8);
    f32x4 s0 = {0.f, 0.f, 0.f, 0.f}, s1 = {0.f, 0.f, 0.f, 0.f};
#pragma unroll
    for (int c = 0; c < 4; ++c) {
      s0 = __builtin_amdgcn_mfma_f32_16x16x32_f16(kf[c], qf[0][c], s0, 0, 0, 0);
      s1 = __builtin_amdgcn_mfma_f32_16x16x32_f16(kf[c], qf[1][c], s1, 0, 0, 0);
    }
    const int kbase = kt * 16 + lg * 4;
    float sc[2][4];
#pragma unroll
    for (int i = 0; i < 4; ++i) {
      sc[0][i] = s0[i] * scale;
      sc[1][i] = s1[i] * scale;
    }
    if (kt >= 2 * qt) {
#pragma unroll
      for (int qc = 0; qc < 2; ++qc)
#pragma unroll
        for (int i = 0; i < 4; ++i)
          if (kbase + i > sq[qc]) sc[qc][i] = NEG;
    }
    half4_t pf[2];
#pragma unroll
    for (int qc = 0; qc < 2; ++qc) {
      float mx = fmaxf(fmaxf(sc[qc][0], sc[qc][1]), fmaxf(sc[qc][2], sc[qc][3]));
      mx = fmaxf(mx, __shfl_xor(mx, 16));
      mx = fmaxf(mx, __shfl_xor(mx, 32));
      if (!__all(mx - m[qc] <= 8.0f)) {  // defer-max (T13)
        float mn = fmaxf(m[qc], mx);
        float corr = exp2f((m[qc] - mn) * LOG2E);
        den[qc] *= corr;
#pragma unroll
        for (int dc = 0; dc < 8; ++dc)
#pragma unroll
          for (int i = 0; i < 4; ++i) acc[dc][qc][i] *= corr;
        m[qc] = mn;
      }
      float ps = 0.f, p[4];
#pragma unroll
      for (int i = 0; i < 4; ++i) {
        p[i] = exp2f((sc[qc][i] - m[qc]) * LOG2E);
        ps += p[i];
      }
      ps += __shfl_xor(ps, 16);
      ps += __shfl_xor(ps, 32);
      den[qc] += ps;
      pf[qc] = (half4_t){(_Float16)p[0], (_Float16)p[1], (_Float16)p[2], (_Float16)p[3]};
    }
#pragma unroll
    for (int dc = 0; dc < 8; ++dc) {
      half4_t vf = *(const half4_t*)(Vb + (size_t)kt * 2048 + (dc * 16 + lr) * 16 + lg * 4);
      acc[dc][0] = __builtin_amdgcn_mfma_f32_16x16x16f16(vf, pf[0], acc[dc][0], 0, 0, 0);
      acc[dc][1] = __builtin_amdgcn_mfma_f32_16x16x16f16(vf, pf[1], acc[dc][1], 0, 0, 0);
    }
  }

  _Float16* Os = Op + (size_t)split * S_LEN * HID;
#pragma unroll
  for (int qc = 0; qc < 2; ++qc) {
    float inv = den[qc] > 0.f ? 1.0f / den[qc] : 0.f;
#pragma unroll
    for (int dc = 0; dc < 8; ++dc) {
      half4_t o;
#pragma unroll
      for (int i = 0; i < 4; ++i) o[i] = (_Float16)(acc[dc][qc][i] * inv);
      *(half4_t*)(Os + (size_t)sq[qc] * HID + h * 128 + dc * 16 + lg * 4) = o;
    }
    if (lg == 0) {
      int mdix = ((split * S_LEN + sq[qc]) * NH + h) * 2;
      Md[mdix] = m[qc];
      Md[mdix + 1] = den[qc];
    }
  }
}

// ---------------- split-KV combine ----------------
__global__ __launch_bounds__(256) void attn_combine(const _Float16* __restrict__ Op,
                                                    const float* __restrict__ Md,
                                                    _Float16* __restrict__ O) {
  const float LOG2E = 1.4426950408889634f;
  int idx = blockIdx.x * 256 + threadIdx.x;
  int dd = (idx & 15) * 8;
  int h = (idx >> 4) & 31;
  int s = idx >> 9;
  int base = (s * NH + h) * 2;
  float m0 = Md[base], den0 = Md[base + 1];
  float m1 = Md[S_LEN * NH * 2 + base], den1 = Md[S_LEN * NH * 2 + base + 1];
  float M = fmaxf(m0, m1);
  float w0 = den0 * exp2f((m0 - M) * LOG2E);
  float w1 = den1 * exp2f((m1 - M) * LOG2E);
  float r = 1.0f / (w0 + w1);
  w0 *= r;
  w1 *= r;
  size_t off = (size_t)s * HID + h * 128 + dd;
  half8_t a = *(const half8_t*)(Op + off);
  half8_t b = *(const half8_t*)(Op + (size_t)S_LEN * HID + off);
  half8_t o;
#pragma unroll
  for (int j = 0; j < 8; ++j) o[j] = (_Float16)(w0 * (float)a[j] + w1 * (float)b[j]);
  *(half8_t*)(O + off) = o;
}

// ---------------- launcher ----------------
extern "C" void kernel_launch(void* const* d_in, const int* in_sizes, int n_in,
                              void* d_out, int out_size, void* d_ws, size_t ws_size,
                              hipStream_t stream) {
  (void)in_sizes; (void)n_in; (void)out_size; (void)ws_size;
  const float* hs = (const float*)d_in[0];
  const float* wq = (const float*)d_in[1];
  const float* wk = (const float*)d_in[2];
  const float* wv = (const float*)d_in[3];
  const float* wo = (const float*)d_in[4];

  char* ws = (char*)d_ws;
  _Float16* hs_h = (_Float16*)(ws);                       // [0,16M): hs f16; later o_h
  _Float16* q_h  = (_Float16*)(ws + (16u << 20));         // [16,32M)
  _Float16* K2   = (_Float16*)(ws + (32u << 20));         // [32,36M): tiled K
  _Float16* V2   = (_Float16*)(ws + (36u << 20));         // [36,40M): tiled V
  float* cost    = (float*)(ws + (40u << 20));            // 512 KiB
  float* sint    = (float*)(ws + (40u << 20) + (512u << 10));
  _Float16* Op   = (_Float16*)(ws + (41u << 20));         // [41,73M): attn partials
  float* Md      = (float*)(ws + (73u << 20));            // [73,75M)
  _Float16* o_h  = hs_h;

  cvt_f32_f16<<<8192, 256, 0, stream>>>(hs, hs_h, (S_LEN * HID) / 4);
  rope_table_kernel<<<(S_LEN * 64) / 256, 256, 0, stream>>>(cost, sint);

  // merged QKV projection: 768 blocks (3/CU), f32 weights read in-kernel
  gemmD<0><<<768, 256, 0, stream>>>(hs_h, wq, wk, wv, q_h, K2, V2);

  rope_apply_q<<<(S_LEN * NH * 16) / 256, 256, 0, stream>>>(q_h, cost, sint);
  rope_k2_inplace<<<(S_LEN * NKV * 16) / 256, 256, 0, stream>>>(K2, cost, sint);

  attn_kernel<<<1024, 256, 0, stream>>>(q_h, K2, V2, Op, Md);
  attn_combine<<<4096, 256, 0, stream>>>(Op, Md, o_h);

  // O-projection: 512 blocks, wo f32 read in-kernel
  gemmD<1><<<512, 256, 0, stream>>>(o_h, wo, nullptr, nullptr, d_out, nullptr, nullptr);
}

// Round 16
// 379.519 us; speedup vs baseline: 1.1538x; 1.1538x over previous
//
#include <hip/hip_runtime.h>
#include <hip/hip_bf16.h>

// MockLlamaAttention R16: B=1, S=2048, HIDDEN=4096, H=32, HKV=8, D=128, G=4.
// R15 (in-GEMM f32 weights) reverted — third confirmation of m151. Base = R13
// (best, 385.5us). Single change: attention inner-loop scheduling:
//   (1) K-prefetch pipeline (kfn for kt+1 issued before kt's QK^T),
//   (2) V-hoist: all 8 vf loads issued between QK^T and softmax (T14),
//   (3) s_setprio(1) around QK^T / PV MFMA clusters (T5, +4-7% attn m191).
// Math identical. GEMM (tri-buffer counted-vmcnt + T2 swizzle), cvts, RoPE
// unchanged from R13. Workspace: 89 MiB peak.

typedef _Float16 half4_t __attribute__((ext_vector_type(4)));
typedef _Float16 half8_t __attribute__((ext_vector_type(8)));
typedef float f32x4 __attribute__((ext_vector_type(4)));

#define S_LEN 2048
#define HID 4096
#define NH 32
#define NKV 8

__device__ __forceinline__ void gload_lds16(const void* g, void* l) {
  __builtin_amdgcn_global_load_lds((const __attribute__((address_space(1))) void*)g,
                                   (__attribute__((address_space(3))) void*)l, 16, 0, 0);
}

// ---------------- fp32 -> f16 convert (vectorized) ----------------
__global__ __launch_bounds__(256) void cvt_f32_f16(const float* __restrict__ src,
                                                   _Float16* __restrict__ dst, int n4) {
  int i = blockIdx.x * 256 + threadIdx.x;
  if (i >= n4) return;
  f32x4 v = *(const f32x4*)(src + (size_t)i * 4);
  half4_t h = {(_Float16)v[0], (_Float16)v[1], (_Float16)v[2], (_Float16)v[3]};
  *(half4_t*)(dst + (size_t)i * 4) = h;
}

// ------- merged wq|wk|wv fp32 -> contiguous f16 [6144][4096] -------
__global__ __launch_bounds__(256) void cvt_qkv(const float* __restrict__ wq,
                                               const float* __restrict__ wk,
                                               const float* __restrict__ wv,
                                               _Float16* __restrict__ dst, int n4) {
  int i = blockIdx.x * 256 + threadIdx.x;  // n4 = 6144*4096/4
  if (i >= n4) return;
  size_t e = (size_t)i * 4;
  const float* src;
  size_t off;
  if (e < (size_t)4096 * 4096)      { src = wq; off = e; }
  else if (e < (size_t)5120 * 4096) { src = wk; off = e - (size_t)4096 * 4096; }
  else                              { src = wv; off = e - (size_t)5120 * 4096; }
  f32x4 v = *(const f32x4*)(src + off);
  half4_t h = {(_Float16)v[0], (_Float16)v[1], (_Float16)v[2], (_Float16)v[3]};
  *(half4_t*)(dst + e) = h;
}

// ---------------- RoPE cos/sin table: [2048][64] fp32 ----------------
__global__ __launch_bounds__(256) void rope_table_kernel(float* __restrict__ cost,
                                                         float* __restrict__ sint) {
  int i = blockIdx.x * 256 + threadIdx.x;
  int d = i & 63;
  int s = i >> 6;
  float inv = exp2f(-(float)d * (13.287712379549449f / 64.0f));
  float f = (float)s * inv;
  cost[i] = cosf(f);
  sint[i] = sinf(f);
}

// ---------------- RoPE apply for Q (in place, [S][NH*128]) ----------------
__global__ __launch_bounds__(256) void rope_apply_q(_Float16* __restrict__ X,
                                                    const float* __restrict__ cost,
                                                    const float* __restrict__ sint) {
  int idx = blockIdx.x * 256 + threadIdx.x;
  int g = idx & 15;
  int tmp = idx >> 4;
  int h = tmp % NH;
  int s = tmp / NH;
  int d0 = g * 4;
  size_t base = (size_t)s * HID + h * 128 + d0;
  half4_t x1 = *(half4_t*)(X + base);
  half4_t x2 = *(half4_t*)(X + base + 64);
  const float* cp = cost + s * 64 + d0;
  const float* sp = sint + s * 64 + d0;
  half4_t y1, y2;
#pragma unroll
  for (int j = 0; j < 4; ++j) {
    float c = cp[j], sn = sp[j];
    float a = (float)x1[j], b = (float)x2[j];
    y1[j] = (_Float16)(a * c - b * sn);
    y2[j] = (_Float16)(b * c + a * sn);
  }
  *(half4_t*)(X + base) = y1;
  *(half4_t*)(X + base + 64) = y2;
}

// ------- RoPE apply for K, in place on tiled K2 [NKV][S/16][d/8][16s][8d] ----
__global__ __launch_bounds__(256) void rope_k2_inplace(_Float16* __restrict__ K2,
                                                       const float* __restrict__ cost,
                                                       const float* __restrict__ sint) {
  int idx = blockIdx.x * 256 + threadIdx.x;  // S*NKV*16
  int g = idx & 15;
  int tmp = idx >> 4;
  int h = tmp % NKV;
  int s = tmp / NKV;
  int d0 = g * 4;
  size_t tb = (size_t)h * (S_LEN * 128) + (size_t)(s >> 4) * 2048 + (size_t)(s & 15) * 8;
  size_t a1 = tb + (size_t)(d0 >> 3) * 128 + (d0 & 7);
  size_t a2 = a1 + 1024;
  half4_t x1 = *(half4_t*)(K2 + a1);
  half4_t x2 = *(half4_t*)(K2 + a2);
  const float* cp = cost + s * 64 + d0;
  const float* sp = sint + s * 64 + d0;
  half4_t y1, y2;
#pragma unroll
  for (int j = 0; j < 4; ++j) {
    float c = cp[j], sn = sp[j];
    float a = (float)x1[j], b = (float)x2[j];
    y1[j] = (_Float16)(a * c - b * sn);
    y2[j] = (_Float16)(b * c + a * sn);
  }
  *(half4_t*)(K2 + a1) = y1;
  *(half4_t*)(K2 + a2) = y2;
}

// ======== GEMM: 128x128, BK=32, tri-buffer counted-vmcnt, T2 swizzle ========
// (identical to R13, verified 797 TF)
template <int MODE>
__global__ __launch_bounds__(256) void gemmT(const _Float16* __restrict__ A,
                                             const _Float16* __restrict__ W,
                                             void* __restrict__ out,
                                             _Float16* __restrict__ K2,
                                             _Float16* __restrict__ V2) {
  const int id = blockIdx.x;
  const int xcd = id & 7, slot = id >> 3;
  const int c = (MODE == 0) ? (xcd * 6 + (slot >> 4)) : (xcd * 4 + (slot >> 4));
  const int m0 = (slot & 15) * 128;
  const int col0 = c * 128;
  __shared__ __align__(16) _Float16 As[3][128 * 32];
  __shared__ __align__(16) _Float16 Bs[3][128 * 32];
  const int t = threadIdx.x, w = t >> 6, l = t & 63, lr = l & 15, lg = l >> 4;
  const int wm = (w >> 1) * 64, wn = (w & 1) * 64;
  const int srow = l >> 2;
  const int scolS = (((l & 3) ^ ((l >> 3) & 3))) * 8;  // T2 swizzle (lane-const)
  const int rc = (lr >> 1) & 3;
  const _Float16* ap = A + (size_t)m0 * 4096 + scolS;
  const _Float16* bp = W + (size_t)col0 * 4096 + scolS;

  f32x4 acc[4][4] = {};

#define STAGE(buf_, kb_)                                              \
  _Pragma("unroll") for (int it = 0; it < 2; ++it) {                  \
    const int ci = it * 4 + w;                                        \
    const int r = ci * 16 + srow;                                     \
    gload_lds16(ap + (size_t)r * 4096 + (kb_), &As[buf_][ci * 512]);  \
    gload_lds16(bp + (size_t)r * 4096 + (kb_), &Bs[buf_][ci * 512]);  \
  }

  STAGE(0, 0)
  STAGE(1, 32)

  for (int k = 0; k < 128; ++k) {
    const int kb2 = (k + 2) * 32;
    const int buf = k % 3;
    __builtin_amdgcn_s_barrier();
    __builtin_amdgcn_sched_barrier(0);
    if (kb2 < 4096) {
      STAGE((k + 2) % 3, kb2)
      asm volatile("s_waitcnt vmcnt(4)" ::: "memory");
    } else {
      asm volatile("s_waitcnt vmcnt(0)" ::: "memory");
    }
    __builtin_amdgcn_sched_barrier(0);
    __builtin_amdgcn_s_barrier();
    half8_t af[4], bf[4];
#pragma unroll
    for (int mi = 0; mi < 4; ++mi)
      af[mi] = *(const half8_t*)&As[buf][(wm + mi * 16 + lr) * 32 + (lg ^ rc) * 8];
#pragma unroll
    for (int ni = 0; ni < 4; ++ni)
      bf[ni] = *(const half8_t*)&Bs[buf][(wn + ni * 16 + lr) * 32 + (lg ^ rc) * 8];
#pragma unroll
    for (int mi = 0; mi < 4; ++mi)
#pragma unroll
      for (int ni = 0; ni < 4; ++ni)
        acc[mi][ni] = __builtin_amdgcn_mfma_f32_16x16x32_f16(af[mi], bf[ni], acc[mi][ni], 0, 0, 0);
  }
#undef STAGE

#pragma unroll
  for (int mi = 0; mi < 4; ++mi) {
#pragma unroll
    for (int ni = 0; ni < 4; ++ni) {
      const int row = m0 + wm + mi * 16 + lg * 4;
      const int col = col0 + wn + ni * 16 + lr;
      if (MODE == 1) {
#pragma unroll
        for (int i = 0; i < 4; ++i)
          ((float*)out)[(size_t)(row + i) * 4096 + col] = acc[mi][ni][i];
      } else {
        if (col < 4096) {
#pragma unroll
          for (int i = 0; i < 4; ++i)
            ((_Float16*)out)[(size_t)(row + i) * 4096 + col] = (_Float16)acc[mi][ni][i];
        } else if (col < 5120) {  // K2 tiled [NKV][S/16][d/8][16s][8d]
          const int cl = col - 4096;
          const int h = cl >> 7, d = cl & 127;
          const size_t kk = (size_t)h * (S_LEN * 128) + (size_t)(row >> 4) * 2048 +
                            (size_t)(d >> 3) * 128 + (d & 7);
#pragma unroll
          for (int i = 0; i < 4; ++i)
            K2[kk + ((row + i) & 15) * 8] = (_Float16)acc[mi][ni][i];
        } else {  // V2 tiled [NKV][S/16][128d][16s]
          const int cl = col - 5120;
          half4_t o;
#pragma unroll
          for (int i = 0; i < 4; ++i) o[i] = (_Float16)acc[mi][ni][i];
          *(half4_t*)(V2 + (size_t)(cl >> 7) * (S_LEN * 128) + (size_t)(row >> 4) * 2048 +
                      (size_t)(cl & 127) * 16 + (row & 15)) = o;
        }
      }
    }
  }
}

// ---------------- Flash attention v5: pipelined loads (split-KV) ----------------
__global__ __launch_bounds__(256) void attn_kernel(const _Float16* __restrict__ Q,
                                                   const _Float16* __restrict__ K2,
                                                   const _Float16* __restrict__ V2,
                                                   _Float16* __restrict__ Op,
                                                   float* __restrict__ Md) {
  const int bid = blockIdx.x;
  const int hk = bid & 7;
  const int split = (bid >> 3) & 1;
  const int qt = 63 - (bid >> 4);
  const int w = threadIdx.x >> 6;
  const int h = hk * 4 + w;
  const int l = threadIdx.x & 63;
  const int lr = l & 15;
  const int lg = l >> 4;
  const float scale = 0.08838834764831845f;
  const float LOG2E = 1.4426950408889634f;
  const float NEG = -1.0e30f;

  const int half_steps = qt + 1;
  const int kt0 = split * half_steps;
  const int kt1 = kt0 + half_steps;

  int sq[2];
  half8_t qf[2][4];
#pragma unroll
  for (int qc = 0; qc < 2; ++qc) {
    sq[qc] = qt * 32 + qc * 16 + lr;
#pragma unroll
    for (int c = 0; c < 4; ++c)
      qf[qc][c] = *(const half8_t*)(Q + (size_t)sq[qc] * HID + h * 128 + c * 32 + lg * 8);
  }
  const _Float16* Kb = K2 + (size_t)hk * (S_LEN * 128);
  const _Float16* Vb = V2 + (size_t)hk * (S_LEN * 128);

  f32x4 acc[8][2] = {};
  float m[2] = {NEG, NEG};
  float den[2] = {0.f, 0.f};

  // K-prefetch pipeline: kfn holds the NEXT step's K fragments
  half8_t kfn[4];
#pragma unroll
  for (int c = 0; c < 4; ++c)
    kfn[c] = *(const half8_t*)(Kb + (size_t)kt0 * 2048 + (c * 4 + lg) * 128 + lr * 8);

  for (int kt = kt0; kt < kt1; ++kt) {
    half8_t kf[4];
#pragma unroll
    for (int c = 0; c < 4; ++c) kf[c] = kfn[c];
    if (kt + 1 < kt1) {  // issue next-K loads before this step's compute
#pragma unroll
      for (int c = 0; c < 4; ++c)
        kfn[c] = *(const half8_t*)(Kb + (size_t)(kt + 1) * 2048 + (c * 4 + lg) * 128 + lr * 8);
    }
    f32x4 s0 = {0.f, 0.f, 0.f, 0.f}, s1 = {0.f, 0.f, 0.f, 0.f};
    __builtin_amdgcn_s_setprio(1);
#pragma unroll
    for (int c = 0; c < 4; ++c) {
      s0 = __builtin_amdgcn_mfma_f32_16x16x32_f16(kf[c], qf[0][c], s0, 0, 0, 0);
      s1 = __builtin_amdgcn_mfma_f32_16x16x32_f16(kf[c], qf[1][c], s1, 0, 0, 0);
    }
    __builtin_amdgcn_s_setprio(0);
    // V-hoist (T14): issue all 8 V loads now; latency hides under softmax
    half4_t vf[8];
#pragma unroll
    for (int dc = 0; dc < 8; ++dc)
      vf[dc] = *(const half4_t*)(Vb + (size_t)kt * 2048 + (dc * 16 + lr) * 16 + lg * 4);
    const int kbase = kt * 16 + lg * 4;
    float sc[2][4];
#pragma unroll
    for (int i = 0; i < 4; ++i) {
      sc[0][i] = s0[i] * scale;
      sc[1][i] = s1[i] * scale;
    }
    if (kt >= 2 * qt) {
#pragma unroll
      for (int qc = 0; qc < 2; ++qc)
#pragma unroll
        for (int i = 0; i < 4; ++i)
          if (kbase + i > sq[qc]) sc[qc][i] = NEG;
    }
    half4_t pf[2];
#pragma unroll
    for (int qc = 0; qc < 2; ++qc) {
      float mx = fmaxf(fmaxf(sc[qc][0], sc[qc][1]), fmaxf(sc[qc][2], sc[qc][3]));
      mx = fmaxf(mx, __shfl_xor(mx, 16));
      mx = fmaxf(mx, __shfl_xor(mx, 32));
      if (!__all(mx - m[qc] <= 8.0f)) {  // defer-max (T13)
        float mn = fmaxf(m[qc], mx);
        float corr = exp2f((m[qc] - mn) * LOG2E);
        den[qc] *= corr;
#pragma unroll
        for (int dc = 0; dc < 8; ++dc)
#pragma unroll
          for (int i = 0; i < 4; ++i) acc[dc][qc][i] *= corr;
        m[qc] = mn;
      }
      float ps = 0.f, p[4];
#pragma unroll
      for (int i = 0; i < 4; ++i) {
        p[i] = exp2f((sc[qc][i] - m[qc]) * LOG2E);
        ps += p[i];
      }
      ps += __shfl_xor(ps, 16);
      ps += __shfl_xor(ps, 32);
      den[qc] += ps;
      pf[qc] = (half4_t){(_Float16)p[0], (_Float16)p[1], (_Float16)p[2], (_Float16)p[3]};
    }
    __builtin_amdgcn_s_setprio(1);
#pragma unroll
    for (int dc = 0; dc < 8; ++dc) {
      acc[dc][0] = __builtin_amdgcn_mfma_f32_16x16x16f16(vf[dc], pf[0], acc[dc][0], 0, 0, 0);
      acc[dc][1] = __builtin_amdgcn_mfma_f32_16x16x16f16(vf[dc], pf[1], acc[dc][1], 0, 0, 0);
    }
    __builtin_amdgcn_s_setprio(0);
  }

  _Float16* Os = Op + (size_t)split * S_LEN * HID;
#pragma unroll
  for (int qc = 0; qc < 2; ++qc) {
    float inv = den[qc] > 0.f ? 1.0f / den[qc] : 0.f;
#pragma unroll
    for (int dc = 0; dc < 8; ++dc) {
      half4_t o;
#pragma unroll
      for (int i = 0; i < 4; ++i) o[i] = (_Float16)(acc[dc][qc][i] * inv);
      *(half4_t*)(Os + (size_t)sq[qc] * HID + h * 128 + dc * 16 + lg * 4) = o;
    }
    if (lg == 0) {
      int mdix = ((split * S_LEN + sq[qc]) * NH + h) * 2;
      Md[mdix] = m[qc];
      Md[mdix + 1] = den[qc];
    }
  }
}

// ---------------- split-KV combine ----------------
__global__ __launch_bounds__(256) void attn_combine(const _Float16* __restrict__ Op,
                                                    const float* __restrict__ Md,
                                                    _Float16* __restrict__ O) {
  const float LOG2E = 1.4426950408889634f;
  int idx = blockIdx.x * 256 + threadIdx.x;
  int dd = (idx & 15) * 8;
  int h = (idx >> 4) & 31;
  int s = idx >> 9;
  int base = (s * NH + h) * 2;
  float m0 = Md[base], den0 = Md[base + 1];
  float m1 = Md[S_LEN * NH * 2 + base], den1 = Md[S_LEN * NH * 2 + base + 1];
  float M = fmaxf(m0, m1);
  float w0 = den0 * exp2f((m0 - M) * LOG2E);
  float w1 = den1 * exp2f((m1 - M) * LOG2E);
  float r = 1.0f / (w0 + w1);
  w0 *= r;
  w1 *= r;
  size_t off = (size_t)s * HID + h * 128 + dd;
  half8_t a = *(const half8_t*)(Op + off);
  half8_t b = *(const half8_t*)(Op + (size_t)S_LEN * HID + off);
  half8_t o;
#pragma unroll
  for (int j = 0; j < 8; ++j) o[j] = (_Float16)(w0 * (float)a[j] + w1 * (float)b[j]);
  *(half8_t*)(O + off) = o;
}

// ---------------- launcher ----------------
extern "C" void kernel_launch(void* const* d_in, const int* in_sizes, int n_in,
                              void* d_out, int out_size, void* d_ws, size_t ws_size,
                              hipStream_t stream) {
  (void)in_sizes; (void)n_in; (void)out_size; (void)ws_size;
  const float* hs = (const float*)d_in[0];
  const float* wq = (const float*)d_in[1];
  const float* wk = (const float*)d_in[2];
  const float* wv = (const float*)d_in[3];
  const float* wo = (const float*)d_in[4];

  char* ws = (char*)d_ws;
  _Float16* hs_h = (_Float16*)(ws);                       // [0,16M): hs f16; later o_h
  _Float16* q_h  = (_Float16*)(ws + (16u << 20));         // [16,32M)
  _Float16* K2   = (_Float16*)(ws + (32u << 20));         // [32,36M): tiled K
  _Float16* V2   = (_Float16*)(ws + (36u << 20));         // [36,40M): tiled V
  float* cost    = (float*)(ws + (40u << 20));            // 512 KiB
  float* sint    = (float*)(ws + (40u << 20) + (512u << 10));
  _Float16* wqkv = (_Float16*)(ws + (41u << 20));         // [41,89M): merged f16 weights
  _Float16* Op   = wqkv;                                  // [41,73M): attn partials (wqkv dead)
  float* Md      = (float*)(ws + (73u << 20));            // [73,75M)
  _Float16* wo_h = wqkv;                                  // [41,73M): wo f16 (Op dead)
  _Float16* o_h  = hs_h;

  cvt_f32_f16<<<8192, 256, 0, stream>>>(hs, hs_h, (S_LEN * HID) / 4);
  rope_table_kernel<<<(S_LEN * 64) / 256, 256, 0, stream>>>(cost, sint);
  cvt_qkv<<<24576, 256, 0, stream>>>(wq, wk, wv, wqkv, (6144 * 4096) / 4);

  // merged QKV projection: 768 blocks (3/CU), weight-once XCD decode
  gemmT<0><<<768, 256, 0, stream>>>(hs_h, wqkv, q_h, K2, V2);

  rope_apply_q<<<(S_LEN * NH * 16) / 256, 256, 0, stream>>>(q_h, cost, sint);
  rope_k2_inplace<<<(S_LEN * NKV * 16) / 256, 256, 0, stream>>>(K2, cost, sint);

  attn_kernel<<<1024, 256, 0, stream>>>(q_h, K2, V2, Op, Md);
  attn_combine<<<4096, 256, 0, stream>>>(Op, Md, o_h);

  cvt_f32_f16<<<16384, 256, 0, stream>>>(wo, wo_h, (HID * HID) / 4);
  gemmT<1><<<512, 256, 0, stream>>>(o_h, wo_h, d_out, nullptr, nullptr);
}

// Round 18
// 377.881 us; speedup vs baseline: 1.1588x; 1.0043x over previous
//
#include <hip/hip_runtime.h>
#include <hip/hip_bf16.h>

// MockLlamaAttention R18 == R16 exactly (revert of R17's launch fusion, which
// failed absmax 0.146 on an unidentifiable path; R16 passed at 379.5us).
// B=1, S=2048, HIDDEN=4096, H=32, HKV=8, D=128, G=4.
// GEMMs: 128^2 BK=32 tri-buffer counted-vmcnt + T2 swizzle (797 TF, 0 bank
// conflicts). Attention: split-KV, tiled K2/V2, K-prefetch + V-hoist + setprio.
// Workspace: 89 MiB peak.

typedef _Float16 half4_t __attribute__((ext_vector_type(4)));
typedef _Float16 half8_t __attribute__((ext_vector_type(8)));
typedef float f32x4 __attribute__((ext_vector_type(4)));

#define S_LEN 2048
#define HID 4096
#define NH 32
#define NKV 8

__device__ __forceinline__ void gload_lds16(const void* g, void* l) {
  __builtin_amdgcn_global_load_lds((const __attribute__((address_space(1))) void*)g,
                                   (__attribute__((address_space(3))) void*)l, 16, 0, 0);
}

// ---------------- fp32 -> f16 convert (vectorized) ----------------
__global__ __launch_bounds__(256) void cvt_f32_f16(const float* __restrict__ src,
                                                   _Float16* __restrict__ dst, int n4) {
  int i = blockIdx.x * 256 + threadIdx.x;
  if (i >= n4) return;
  f32x4 v = *(const f32x4*)(src + (size_t)i * 4);
  half4_t h = {(_Float16)v[0], (_Float16)v[1], (_Float16)v[2], (_Float16)v[3]};
  *(half4_t*)(dst + (size_t)i * 4) = h;
}

// ------- merged wq|wk|wv fp32 -> contiguous f16 [6144][4096] -------
__global__ __launch_bounds__(256) void cvt_qkv(const float* __restrict__ wq,
                                               const float* __restrict__ wk,
                                               const float* __restrict__ wv,
                                               _Float16* __restrict__ dst, int n4) {
  int i = blockIdx.x * 256 + threadIdx.x;  // n4 = 6144*4096/4
  if (i >= n4) return;
  size_t e = (size_t)i * 4;
  const float* src;
  size_t off;
  if (e < (size_t)4096 * 4096)      { src = wq; off = e; }
  else if (e < (size_t)5120 * 4096) { src = wk; off = e - (size_t)4096 * 4096; }
  else                              { src = wv; off = e - (size_t)5120 * 4096; }
  f32x4 v = *(const f32x4*)(src + off);
  half4_t h = {(_Float16)v[0], (_Float16)v[1], (_Float16)v[2], (_Float16)v[3]};
  *(half4_t*)(dst + e) = h;
}

// ---------------- RoPE cos/sin table: [2048][64] fp32 ----------------
__global__ __launch_bounds__(256) void rope_table_kernel(float* __restrict__ cost,
                                                         float* __restrict__ sint) {
  int i = blockIdx.x * 256 + threadIdx.x;
  int d = i & 63;
  int s = i >> 6;
  float inv = exp2f(-(float)d * (13.287712379549449f / 64.0f));
  float f = (float)s * inv;
  cost[i] = cosf(f);
  sint[i] = sinf(f);
}

// ---------------- RoPE apply for Q (in place, [S][NH*128]) ----------------
__global__ __launch_bounds__(256) void rope_apply_q(_Float16* __restrict__ X,
                                                    const float* __restrict__ cost,
                                                    const float* __restrict__ sint) {
  int idx = blockIdx.x * 256 + threadIdx.x;
  int g = idx & 15;
  int tmp = idx >> 4;
  int h = tmp % NH;
  int s = tmp / NH;
  int d0 = g * 4;
  size_t base = (size_t)s * HID + h * 128 + d0;
  half4_t x1 = *(half4_t*)(X + base);
  half4_t x2 = *(half4_t*)(X + base + 64);
  const float* cp = cost + s * 64 + d0;
  const float* sp = sint + s * 64 + d0;
  half4_t y1, y2;
#pragma unroll
  for (int j = 0; j < 4; ++j) {
    float c = cp[j], sn = sp[j];
    float a = (float)x1[j], b = (float)x2[j];
    y1[j] = (_Float16)(a * c - b * sn);
    y2[j] = (_Float16)(b * c + a * sn);
  }
  *(half4_t*)(X + base) = y1;
  *(half4_t*)(X + base + 64) = y2;
}

// ------- RoPE apply for K, in place on tiled K2 [NKV][S/16][d/8][16s][8d] ----
__global__ __launch_bounds__(256) void rope_k2_inplace(_Float16* __restrict__ K2,
                                                       const float* __restrict__ cost,
                                                       const float* __restrict__ sint) {
  int idx = blockIdx.x * 256 + threadIdx.x;  // S*NKV*16
  int g = idx & 15;
  int tmp = idx >> 4;
  int h = tmp % NKV;
  int s = tmp / NKV;
  int d0 = g * 4;
  size_t tb = (size_t)h * (S_LEN * 128) + (size_t)(s >> 4) * 2048 + (size_t)(s & 15) * 8;
  size_t a1 = tb + (size_t)(d0 >> 3) * 128 + (d0 & 7);
  size_t a2 = a1 + 1024;
  half4_t x1 = *(half4_t*)(K2 + a1);
  half4_t x2 = *(half4_t*)(K2 + a2);
  const float* cp = cost + s * 64 + d0;
  const float* sp = sint + s * 64 + d0;
  half4_t y1, y2;
#pragma unroll
  for (int j = 0; j < 4; ++j) {
    float c = cp[j], sn = sp[j];
    float a = (float)x1[j], b = (float)x2[j];
    y1[j] = (_Float16)(a * c - b * sn);
    y2[j] = (_Float16)(b * c + a * sn);
  }
  *(half4_t*)(K2 + a1) = y1;
  *(half4_t*)(K2 + a2) = y2;
}

// ======== GEMM: 128x128, BK=32, tri-buffer counted-vmcnt, T2 swizzle ========
// (identical to R13/R16, verified 797 TF)
template <int MODE>
__global__ __launch_bounds__(256) void gemmT(const _Float16* __restrict__ A,
                                             const _Float16* __restrict__ W,
                                             void* __restrict__ out,
                                             _Float16* __restrict__ K2,
                                             _Float16* __restrict__ V2) {
  const int id = blockIdx.x;
  const int xcd = id & 7, slot = id >> 3;
  const int c = (MODE == 0) ? (xcd * 6 + (slot >> 4)) : (xcd * 4 + (slot >> 4));
  const int m0 = (slot & 15) * 128;
  const int col0 = c * 128;
  __shared__ __align__(16) _Float16 As[3][128 * 32];
  __shared__ __align__(16) _Float16 Bs[3][128 * 32];
  const int t = threadIdx.x, w = t >> 6, l = t & 63, lr = l & 15, lg = l >> 4;
  const int wm = (w >> 1) * 64, wn = (w & 1) * 64;
  const int srow = l >> 2;
  const int scolS = (((l & 3) ^ ((l >> 3) & 3))) * 8;  // T2 swizzle (lane-const)
  const int rc = (lr >> 1) & 3;
  const _Float16* ap = A + (size_t)m0 * 4096 + scolS;
  const _Float16* bp = W + (size_t)col0 * 4096 + scolS;

  f32x4 acc[4][4] = {};

#define STAGE(buf_, kb_)                                              \
  _Pragma("unroll") for (int it = 0; it < 2; ++it) {                  \
    const int ci = it * 4 + w;                                        \
    const int r = ci * 16 + srow;                                     \
    gload_lds16(ap + (size_t)r * 4096 + (kb_), &As[buf_][ci * 512]);  \
    gload_lds16(bp + (size_t)r * 4096 + (kb_), &Bs[buf_][ci * 512]);  \
  }

  STAGE(0, 0)
  STAGE(1, 32)

  for (int k = 0; k < 128; ++k) {
    const int kb2 = (k + 2) * 32;
    const int buf = k % 3;
    __builtin_amdgcn_s_barrier();
    __builtin_amdgcn_sched_barrier(0);
    if (kb2 < 4096) {
      STAGE((k + 2) % 3, kb2)
      asm volatile("s_waitcnt vmcnt(4)" ::: "memory");
    } else {
      asm volatile("s_waitcnt vmcnt(0)" ::: "memory");
    }
    __builtin_amdgcn_sched_barrier(0);
    __builtin_amdgcn_s_barrier();
    half8_t af[4], bf[4];
#pragma unroll
    for (int mi = 0; mi < 4; ++mi)
      af[mi] = *(const half8_t*)&As[buf][(wm + mi * 16 + lr) * 32 + (lg ^ rc) * 8];
#pragma unroll
    for (int ni = 0; ni < 4; ++ni)
      bf[ni] = *(const half8_t*)&Bs[buf][(wn + ni * 16 + lr) * 32 + (lg ^ rc) * 8];
#pragma unroll
    for (int mi = 0; mi < 4; ++mi)
#pragma unroll
      for (int ni = 0; ni < 4; ++ni)
        acc[mi][ni] = __builtin_amdgcn_mfma_f32_16x16x32_f16(af[mi], bf[ni], acc[mi][ni], 0, 0, 0);
  }
#undef STAGE

#pragma unroll
  for (int mi = 0; mi < 4; ++mi) {
#pragma unroll
    for (int ni = 0; ni < 4; ++ni) {
      const int row = m0 + wm + mi * 16 + lg * 4;
      const int col = col0 + wn + ni * 16 + lr;
      if (MODE == 1) {
#pragma unroll
        for (int i = 0; i < 4; ++i)
          ((float*)out)[(size_t)(row + i) * 4096 + col] = acc[mi][ni][i];
      } else {
        if (col < 4096) {
#pragma unroll
          for (int i = 0; i < 4; ++i)
            ((_Float16*)out)[(size_t)(row + i) * 4096 + col] = (_Float16)acc[mi][ni][i];
        } else if (col < 5120) {  // K2 tiled [NKV][S/16][d/8][16s][8d]
          const int cl = col - 4096;
          const int h = cl >> 7, d = cl & 127;
          const size_t kk = (size_t)h * (S_LEN * 128) + (size_t)(row >> 4) * 2048 +
                            (size_t)(d >> 3) * 128 + (d & 7);
#pragma unroll
          for (int i = 0; i < 4; ++i)
            K2[kk + ((row + i) & 15) * 8] = (_Float16)acc[mi][ni][i];
        } else {  // V2 tiled [NKV][S/16][128d][16s]
          const int cl = col - 5120;
          half4_t o;
#pragma unroll
          for (int i = 0; i < 4; ++i) o[i] = (_Float16)acc[mi][ni][i];
          *(half4_t*)(V2 + (size_t)(cl >> 7) * (S_LEN * 128) + (size_t)(row >> 4) * 2048 +
                      (size_t)(cl & 127) * 16 + (row & 15)) = o;
        }
      }
    }
  }
}

// ---------------- Flash attention v5: pipelined loads (split-KV) ----------------
__global__ __launch_bounds__(256) void attn_kernel(const _Float16* __restrict__ Q,
                                                   const _Float16* __restrict__ K2,
                                                   const _Float16* __restrict__ V2,
                                                   _Float16* __restrict__ Op,
                                                   float* __restrict__ Md) {
  const int bid = blockIdx.x;
  const int hk = bid & 7;
  const int split = (bid >> 3) & 1;
  const int qt = 63 - (bid >> 4);
  const int w = threadIdx.x >> 6;
  const int h = hk * 4 + w;
  const int l = threadIdx.x & 63;
  const int lr = l & 15;
  const int lg = l >> 4;
  const float scale = 0.08838834764831845f;
  const float LOG2E = 1.4426950408889634f;
  const float NEG = -1.0e30f;

  const int half_steps = qt + 1;
  const int kt0 = split * half_steps;
  const int kt1 = kt0 + half_steps;

  int sq[2];
  half8_t qf[2][4];
#pragma unroll
  for (int qc = 0; qc < 2; ++qc) {
    sq[qc] = qt * 32 + qc * 16 + lr;
#pragma unroll
    for (int c = 0; c < 4; ++c)
      qf[qc][c] = *(const half8_t*)(Q + (size_t)sq[qc] * HID + h * 128 + c * 32 + lg * 8);
  }
  const _Float16* Kb = K2 + (size_t)hk * (S_LEN * 128);
  const _Float16* Vb = V2 + (size_t)hk * (S_LEN * 128);

  f32x4 acc[8][2] = {};
  float m[2] = {NEG, NEG};
  float den[2] = {0.f, 0.f};

  half8_t kfn[4];
#pragma unroll
  for (int c = 0; c < 4; ++c)
    kfn[c] = *(const half8_t*)(Kb + (size_t)kt0 * 2048 + (c * 4 + lg) * 128 + lr * 8);

  for (int kt = kt0; kt < kt1; ++kt) {
    half8_t kf[4];
#pragma unroll
    for (int c = 0; c < 4; ++c) kf[c] = kfn[c];
    if (kt + 1 < kt1) {
#pragma unroll
      for (int c = 0; c < 4; ++c)
        kfn[c] = *(const half8_t*)(Kb + (size_t)(kt + 1) * 2048 + (c * 4 + lg) * 128 + lr * 8);
    }
    f32x4 s0 = {0.f, 0.f, 0.f, 0.f}, s1 = {0.f, 0.f, 0.f, 0.f};
    __builtin_amdgcn_s_setprio(1);
#pragma unroll
    for (int c = 0; c < 4; ++c) {
      s0 = __builtin_amdgcn_mfma_f32_16x16x32_f16(kf[c], qf[0][c], s0, 0, 0, 0);
      s1 = __builtin_amdgcn_mfma_f32_16x16x32_f16(kf[c], qf[1][c], s1, 0, 0, 0);
    }
    __builtin_amdgcn_s_setprio(0);
    half4_t vf[8];
#pragma unroll
    for (int dc = 0; dc < 8; ++dc)
      vf[dc] = *(const half4_t*)(Vb + (size_t)kt * 2048 + (dc * 16 + lr) * 16 + lg * 4);
    const int kbase = kt * 16 + lg * 4;
    float sc[2][4];
#pragma unroll
    for (int i = 0; i < 4; ++i) {
      sc[0][i] = s0[i] * scale;
      sc[1][i] = s1[i] * scale;
    }
    if (kt >= 2 * qt) {
#pragma unroll
      for (int qc = 0; qc < 2; ++qc)
#pragma unroll
        for (int i = 0; i < 4; ++i)
          if (kbase + i > sq[qc]) sc[qc][i] = NEG;
    }
    half4_t pf[2];
#pragma unroll
    for (int qc = 0; qc < 2; ++qc) {
      float mx = fmaxf(fmaxf(sc[qc][0], sc[qc][1]), fmaxf(sc[qc][2], sc[qc][3]));
      mx = fmaxf(mx, __shfl_xor(mx, 16));
      mx = fmaxf(mx, __shfl_xor(mx, 32));
      if (!__all(mx - m[qc] <= 8.0f)) {  // defer-max (T13)
        float mn = fmaxf(m[qc], mx);
        float corr = exp2f((m[qc] - mn) * LOG2E);
        den[qc] *= corr;
#pragma unroll
        for (int dc = 0; dc < 8; ++dc)
#pragma unroll
          for (int i = 0; i < 4; ++i) acc[dc][qc][i] *= corr;
        m[qc] = mn;
      }
      float ps = 0.f, p[4];
#pragma unroll
      for (int i = 0; i < 4; ++i) {
        p[i] = exp2f((sc[qc][i] - m[qc]) * LOG2E);
        ps += p[i];
      }
      ps += __shfl_xor(ps, 16);
      ps += __shfl_xor(ps, 32);
      den[qc] += ps;
      pf[qc] = (half4_t){(_Float16)p[0], (_Float16)p[1], (_Float16)p[2], (_Float16)p[3]};
    }
    __builtin_amdgcn_s_setprio(1);
#pragma unroll
    for (int dc = 0; dc < 8; ++dc) {
      acc[dc][0] = __builtin_amdgcn_mfma_f32_16x16x16f16(vf[dc], pf[0], acc[dc][0], 0, 0, 0);
      acc[dc][1] = __builtin_amdgcn_mfma_f32_16x16x16f16(vf[dc], pf[1], acc[dc][1], 0, 0, 0);
    }
    __builtin_amdgcn_s_setprio(0);
  }

  _Float16* Os = Op + (size_t)split * S_LEN * HID;
#pragma unroll
  for (int qc = 0; qc < 2; ++qc) {
    float inv = den[qc] > 0.f ? 1.0f / den[qc] : 0.f;
#pragma unroll
    for (int dc = 0; dc < 8; ++dc) {
      half4_t o;
#pragma unroll
      for (int i = 0; i < 4; ++i) o[i] = (_Float16)(acc[dc][qc][i] * inv);
      *(half4_t*)(Os + (size_t)sq[qc] * HID + h * 128 + dc * 16 + lg * 4) = o;
    }
    if (lg == 0) {
      int mdix = ((split * S_LEN + sq[qc]) * NH + h) * 2;
      Md[mdix] = m[qc];
      Md[mdix + 1] = den[qc];
    }
  }
}

// ---------------- split-KV combine ----------------
__global__ __launch_bounds__(256) void attn_combine(const _Float16* __restrict__ Op,
                                                    const float* __restrict__ Md,
                                                    _Float16* __restrict__ O) {
  const float LOG2E = 1.4426950408889634f;
  int idx = blockIdx.x * 256 + threadIdx.x;
  int dd = (idx & 15) * 8;
  int h = (idx >> 4) & 31;
  int s = idx >> 9;
  int base = (s * NH + h) * 2;
  float m0 = Md[base], den0 = Md[base + 1];
  float m1 = Md[S_LEN * NH * 2 + base], den1 = Md[S_LEN * NH * 2 + base + 1];
  float M = fmaxf(m0, m1);
  float w0 = den0 * exp2f((m0 - M) * LOG2E);
  float w1 = den1 * exp2f((m1 - M) * LOG2E);
  float r = 1.0f / (w0 + w1);
  w0 *= r;
  w1 *= r;
  size_t off = (size_t)s * HID + h * 128 + dd;
  half8_t a = *(const half8_t*)(Op + off);
  half8_t b = *(const half8_t*)(Op + (size_t)S_LEN * HID + off);
  half8_t o;
#pragma unroll
  for (int j = 0; j < 8; ++j) o[j] = (_Float16)(w0 * (float)a[j] + w1 * (float)b[j]);
  *(half8_t*)(O + off) = o;
}

// ---------------- launcher ----------------
extern "C" void kernel_launch(void* const* d_in, const int* in_sizes, int n_in,
                              void* d_out, int out_size, void* d_ws, size_t ws_size,
                              hipStream_t stream) {
  (void)in_sizes; (void)n_in; (void)out_size; (void)ws_size;
  const float* hs = (const float*)d_in[0];
  const float* wq = (const float*)d_in[1];
  const float* wk = (const float*)d_in[2];
  const float* wv = (const float*)d_in[3];
  const float* wo = (const float*)d_in[4];

  char* ws = (char*)d_ws;
  _Float16* hs_h = (_Float16*)(ws);                       // [0,16M): hs f16; later o_h
  _Float16* q_h  = (_Float16*)(ws + (16u << 20));         // [16,32M)
  _Float16* K2   = (_Float16*)(ws + (32u << 20));         // [32,36M): tiled K
  _Float16* V2   = (_Float16*)(ws + (36u << 20));         // [36,40M): tiled V
  float* cost    = (float*)(ws + (40u << 20));            // 512 KiB
  float* sint    = (float*)(ws + (40u << 20) + (512u << 10));
  _Float16* wqkv = (_Float16*)(ws + (41u << 20));         // [41,89M): merged f16 weights
  _Float16* Op   = wqkv;                                  // [41,73M): attn partials (wqkv dead)
  float* Md      = (float*)(ws + (73u << 20));            // [73,75M)
  _Float16* wo_h = wqkv;                                  // [41,73M): wo f16 (Op dead)
  _Float16* o_h  = hs_h;

  cvt_f32_f16<<<8192, 256, 0, stream>>>(hs, hs_h, (S_LEN * HID) / 4);
  rope_table_kernel<<<(S_LEN * 64) / 256, 256, 0, stream>>>(cost, sint);
  cvt_qkv<<<24576, 256, 0, stream>>>(wq, wk, wv, wqkv, (6144 * 4096) / 4);

  // merged QKV projection: 768 blocks (3/CU), weight-once XCD decode
  gemmT<0><<<768, 256, 0, stream>>>(hs_h, wqkv, q_h, K2, V2);

  rope_apply_q<<<(S_LEN * NH * 16) / 256, 256, 0, stream>>>(q_h, cost, sint);
  rope_k2_inplace<<<(S_LEN * NKV * 16) / 256, 256, 0, stream>>>(K2, cost, sint);

  attn_kernel<<<1024, 256, 0, stream>>>(q_h, K2, V2, Op, Md);
  attn_combine<<<4096, 256, 0, stream>>>(Op, Md, o_h);

  cvt_f32_f16<<<16384, 256, 0, stream>>>(wo, wo_h, (HID * HID) / 4);
  gemmT<1><<<512, 256, 0, stream>>>(o_h, wo_h, d_out, nullptr, nullptr);
}